// Round 13
// baseline (582.606 us; speedup 1.0000x reference)
//
#include <hip/hip_runtime.h>
#include <math.h>

#define D_TOT 480

typedef short bf16x8 __attribute__((ext_vector_type(8)));
typedef float f32x4 __attribute__((ext_vector_type(4)));

#define MFMA16(a, b, c) __builtin_amdgcn_mfma_f32_16x16x32_bf16((a), (b), (c), 0, 0, 0)

static __device__ __forceinline__ unsigned short f2bf(float x) {
  unsigned u = __float_as_uint(x);
  u += 0x7FFFu + ((u >> 16) & 1u);   // RNE (inputs finite)
  return (unsigned short)(u >> 16);
}

// ---------------------------------------------------------------------------
// K0 (templated impl): fused precompute + pack, one 32-k-row strip per block.
// (R10 verbatim — proven fast.)
// ---------------------------------------------------------------------------
template <int M, int DEG, int BASE>
static __device__ void precompute_impl(
    const float* __restrict__ Wq, const float* __restrict__ Wk,
    const float* __restrict__ Wd, const float* __restrict__ Wv,
    unsigned short* __restrict__ Bp, int kt, float* lds) {
  float* sWkT = lds;                 // M*(M+1)
  float* sT   = lds + M * (M + 1);   // 32*M

  constexpr int TPR = 256 / M;
  constexpr int RPT = 32 / TPR;
  constexpr int nct = M / 8;
  constexpr int ktn = M / 32;

  int t = threadIdx.x;
  float scale = 1.0f / ((float)M * (float)M * sqrtf(1440.0f * (float)DEG));
  float sm = rsqrtf((float)M);

  for (int i = t; i < M * M; i += 256) {
    int r = i / M, c = i - r * M;
    sWkT[c * (M + 1) + r] = Wk[i];
  }
  {
    int c = t % M, r0 = t / M;
    float acc[RPT];
#pragma unroll
    for (int rr = 0; rr < RPT; ++rr) acc[rr] = 0.f;
#pragma unroll 4
    for (int a = 0; a < M; ++a) {
      float wd = Wd[a * M + c];
#pragma unroll
      for (int rr = 0; rr < RPT; ++rr)
        acc[rr] += Wq[(kt * 32 + r0 + rr * TPR) * M + a] * wd;
    }
    __syncthreads();
#pragma unroll
    for (int rr = 0; rr < RPT; ++rr) sT[(r0 + rr * TPR) * M + c] = acc[rr];
  }
  __syncthreads();
  {
    int j = t % M, r0 = t / M;
    float acc[RPT];
#pragma unroll
    for (int rr = 0; rr < RPT; ++rr) acc[rr] = 0.f;
#pragma unroll 4
    for (int c = 0; c < M; ++c) {
      float wk = sWkT[c * (M + 1) + j];
#pragma unroll
      for (int rr = 0; rr < RPT; ++rr)
        acc[rr] += sT[(r0 + rr * TPR) * M + c] * wk;
    }
    __syncthreads();
#pragma unroll
    for (int rr = 0; rr < RPT; ++rr) sT[(r0 + rr * TPR) * M + j] = acc[rr] * scale;
  }
  __syncthreads();
  for (int idx = t; idx < nct * 512; idx += 256) {
    int ct = idx >> 9, rem = idx & 511, l = rem >> 3, j = rem & 7;
    int kl = (l >> 4) * 8 + j;
    int c = ct * 16 + (l & 15);
    float val = (c < M) ? sT[kl * M + c] : Wv[(kt * 32 + kl) * M + (c - M)] * sm;
    Bp[BASE + (ct * ktn + kt) * 512 + rem] = f2bf(val);
  }
}

__global__ __launch_bounds__(256) void precompute_all(
    const float* __restrict__ Wq0, const float* __restrict__ Wq1, const float* __restrict__ Wq2,
    const float* __restrict__ Wk0, const float* __restrict__ Wk1, const float* __restrict__ Wk2,
    const float* __restrict__ Wd0, const float* __restrict__ Wd1, const float* __restrict__ Wd2,
    const float* __restrict__ Wv0, const float* __restrict__ Wv1, const float* __restrict__ Wv2,
    unsigned short* __restrict__ Bp) {
  extern __shared__ float lds[];
  int b = blockIdx.x;
  if (b < 4)      precompute_impl<128, 1, 0>(Wq0, Wk0, Wd0, Wv0, Bp, b, lds);
  else if (b < 6) precompute_impl<64, 3, 32768>(Wq1, Wk1, Wd1, Wv1, Bp, b - 4, lds);
  else            precompute_impl<32, 5, 40960>(Wq2, Wk2, Wd2, Wv2, Bp, 0, lds);
}

// ---------------------------------------------------------------------------
// Fused stationary-B kernel + double-buffered global_load_lds tile staging.
// Tile (16 nodes x 480 f32 = 30 KB) DMA'd to LDS ONCE per block (was 4x
// per-wave global reads).  LDS rows: 1920 B stride, granule-XOR swizzle
// applied on the GLOBAL SOURCE address (dest must stay linear for the
// intrinsic); readers XOR (c>>2)^(row&7).  Double buffer: stage ti+1 right
// after the barrier, lands during gather/u-phase of ti.
// Everything else R10/R12-verbatim (u/v MFMA from register-resident B,
// logit LDS atomics + 3-buffer rotation, segmented flush on graph change).
// ---------------------------------------------------------------------------
__global__ __launch_bounds__(256, 2) void fused_stat_kernel(
    const float* __restrict__ f, const unsigned short* __restrict__ Bpack,
    const int* __restrict__ batch,
    float* __restrict__ outnum, float* __restrict__ norm,
    int N, int tpb, int ntiles) {
  __shared__ __align__(16) char xsmem[2 * 30720];   // 2 x (16 rows x 1920 B)
  __shared__ float lds_logit[3][16];
  int t = threadIdx.x, w = t >> 6, lane = t & 63;
  int q = lane >> 4, lm = lane & 15;

  if (t < 48) ((float*)lds_logit)[t] = 0.f;

  int t0 = blockIdx.x * tpb;
  int t1 = min(t0 + tpb, ntiles);
  if (t0 >= t1) return;   // block-uniform

  const bf16x8* B0f = (const bf16x8*)Bpack;
  const bf16x8* B1f = (const bf16x8*)(Bpack + 32768);
  const bf16x8* B2f = (const bf16x8*)(Bpack + 40960);

  // ---- stationary B fragments (registers, loaded once) ----
  bf16x8 Bu0[2][4], Bv0[2][4], Bu1[2], Bv1[2], Bu2, Bv2;
#pragma unroll
  for (int ctl = 0; ctl < 2; ++ctl)
#pragma unroll
    for (int k = 0; k < 4; ++k) {
      Bu0[ctl][k] = B0f[((2 * w + ctl) * 4 + k) * 64 + lane];
      Bv0[ctl][k] = B0f[((2 * w + ctl + 8) * 4 + k) * 64 + lane];
    }
#pragma unroll
  for (int k = 0; k < 2; ++k) {
    Bu1[k] = B1f[(w * 2 + k) * 64 + lane];
    Bv1[k] = B1f[((w + 4) * 2 + k) * 64 + lane];
  }
  bool has2 = (w >= 2);
  int ct2 = has2 ? (w - 2) : 0;
  Bu2 = B2f[ct2 * 64 + lane];
  Bv2 = B2f[(ct2 + 2) * 64 + lane];

  // ---- DMA stage: 30 x global_load_lds(16B), split across 4 waves ----
  // dest granule D = i*64+lane (linear); logical (row r, granule g):
  // r = D/120, s = D%120, g = s ^ (r&7)  (swizzle folded into SOURCE addr)
  auto stage = [&](int buf, int ti2) {
    int nt2 = ti2 * 16;
    int vmax = min(16, N - nt2) - 1;
    char* dstbase = xsmem + buf * 30720;
#pragma unroll
    for (int k = 0; k < 8; ++k) {
      int i = w + 4 * k;
      if (i >= 30) break;                     // wave-uniform
      int D = i * 64 + lane;
      int r = D / 120;
      int g = (D - r * 120) ^ (r & 7);
      int rc = r < vmax ? r : vmax;
      const float* src = f + (size_t)(nt2 + rc) * 480 + g * 4;
      __builtin_amdgcn_global_load_lds(
          (const __attribute__((address_space(1))) void*)src,
          (__attribute__((address_space(3))) void*)(dstbase + i * 1024),
          16, 0, 0);
    }
  };

  // ---- cross-tile accumulators ----
  float racc0[2] = {0.f, 0.f};
  float racc1[3] = {0.f, 0.f, 0.f};
  float racc2[5] = {0.f, 0.f, 0.f, 0.f, 0.f};
  float naccw = 0.f;
  int cur_g = -1;

  auto wavered = [&](float s) -> float {
    s += __shfl_xor(s, 16);
    s += __shfl_xor(s, 32);
    return s;
  };
  auto flushf = [&](int g) {
    float* og = outnum + (size_t)g * 480;
#pragma unroll
    for (int ctl = 0; ctl < 2; ++ctl) {
      float s = wavered(racc0[ctl]);
      if (lane < 16) atomicAdd(og + (2 * w + ctl) * 16 + lane, s);
      racc0[ctl] = 0.f;
    }
#pragma unroll
    for (int d = 0; d < 3; ++d) {
      float s = wavered(racc1[d]);
      if (lane < 16) atomicAdd(og + 128 + 3 * (w * 16 + lane) + d, s);
      racc1[d] = 0.f;
    }
    if (has2) {
#pragma unroll
      for (int d = 0; d < 5; ++d) {
        float s = wavered(racc2[d]);
        if (lane < 16) atomicAdd(og + 320 + 5 * (ct2 * 16 + lane) + d, s);
        racc2[d] = 0.f;
      }
    }
    if (w == 0) {
      float s = wavered(naccw);
      if (lane == 0) atomicAdd(norm + g, s);
      naccw = 0.f;
    }
  };

  // prologue: stage first tile
  stage(0, t0);

  int cur = 0;
  for (int ti = t0; ti < t1; ++ti, cur ^= 1) {
    int p = ti % 3;
    int nt = ti * 16;
    int valid = min(16, N - nt);

    __syncthreads();                    // buf[cur] staged (barrier drains vmcnt)
    if (ti + 1 < t1) stage(cur ^ 1, ti + 1);   // prefetch next tile during compute

    const char* xcur = xsmem + cur * 30720;
    // LDS readers (XOR-swizzled granules)
    auto ld4 = [&](int r, int gr) -> float4 {
      return *reinterpret_cast<const float4*>(xcur + r * 1920 + ((gr ^ (r & 7)) << 4));
    };
    auto ldf = [&](int r, int c) -> float {
      return *reinterpret_cast<const float*>(
          xcur + r * 1920 + ((((c >> 2)) ^ (r & 7)) << 4) + ((c & 3) << 2));
    };

    // ---- A-fragments from LDS (row = lm, k-chunk = q) ----
    bf16x8 a0[4], a1[3][2], a2[5];
#pragma unroll
    for (int ks = 0; ks < 4; ++ks) {
      float4 A = ld4(lm, ks * 8 + 2 * q);
      float4 B = ld4(lm, ks * 8 + 2 * q + 1);
      bf16x8 v;
      v[0] = (short)f2bf(A.x); v[1] = (short)f2bf(A.y);
      v[2] = (short)f2bf(A.z); v[3] = (short)f2bf(A.w);
      v[4] = (short)f2bf(B.x); v[5] = (short)f2bf(B.y);
      v[6] = (short)f2bf(B.z); v[7] = (short)f2bf(B.w);
      a0[ks] = v;
    }
#pragma unroll
    for (int d = 0; d < 3; ++d)
#pragma unroll
      for (int h = 0; h < 2; ++h) {
        bf16x8 v;
#pragma unroll
        for (int j = 0; j < 8; ++j)
          v[j] = (short)f2bf(ldf(lm, 128 + 3 * (h * 32 + q * 8 + j) + d));
        a1[d][h] = v;
      }
#pragma unroll
    for (int d = 0; d < 5; ++d) {
      bf16x8 v;
#pragma unroll
      for (int j = 0; j < 8; ++j)
        v[j] = (short)f2bf(ldf(lm, 320 + 5 * (q * 8 + j) + d));
      a2[d] = v;
    }

    // ---- u-phase (slice) + logit dot (x from LDS, f32-exact) ----
    float pl[4] = {0.f, 0.f, 0.f, 0.f};
#pragma unroll
    for (int ctl = 0; ctl < 2; ++ctl) {
      f32x4 u = {0.f, 0.f, 0.f, 0.f};
      u = MFMA16(a0[0], Bu0[ctl][0], u);
      u = MFMA16(a0[1], Bu0[ctl][1], u);
      u = MFMA16(a0[2], Bu0[ctl][2], u);
      u = MFMA16(a0[3], Bu0[ctl][3], u);
      int c = (2 * w + ctl) * 16 + lm;
#pragma unroll
      for (int r = 0; r < 4; ++r) pl[r] += u[r] * ldf(q * 4 + r, c);
    }
#pragma unroll
    for (int d = 0; d < 3; ++d) {
      f32x4 u = {0.f, 0.f, 0.f, 0.f};
      u = MFMA16(a1[d][0], Bu1[0], u);
      u = MFMA16(a1[d][1], Bu1[1], u);
      int c = 128 + 3 * (w * 16 + lm) + d;
#pragma unroll
      for (int r = 0; r < 4; ++r) pl[r] += u[r] * ldf(q * 4 + r, c);
    }
    if (has2) {
#pragma unroll
      for (int d = 0; d < 5; ++d) {
        f32x4 u = {0.f, 0.f, 0.f, 0.f};
        u = MFMA16(a2[d], Bu2, u);
        int c = 320 + 5 * (ct2 * 16 + lm) + d;
#pragma unroll
        for (int r = 0; r < 4; ++r) pl[r] += u[r] * ldf(q * 4 + r, c);
      }
    }
#pragma unroll
    for (int off = 1; off < 16; off <<= 1) {
#pragma unroll
      for (int r = 0; r < 4; ++r) pl[r] += __shfl_xor(pl[r], off);
    }
    if (lm == 0) {
#pragma unroll
      for (int r = 0; r < 4; ++r) atomicAdd(&lds_logit[p][q * 4 + r], pl[r]);
    }
    __syncthreads();

    float wgt[4];
#pragma unroll
    for (int r = 0; r < 4; ++r) {
      int node = q * 4 + r;
      wgt[r] = (node < valid) ? __expf(lds_logit[p][node]) : 0.f;
    }
    if (t < 16) lds_logit[(ti + 2) % 3][t] = 0.f;   // rotate (3-buffer, race-free)

    // ---- segmented v accumulation over sorted batch ----
    {
      int nn = nt + (lm < valid ? lm : valid - 1);
      if (nn >= N) nn = N - 1;
      int gl = batch[nn];
      int gp = __shfl(gl, (lane == 0) ? 0 : lane - 1);
      unsigned long long bm = __ballot(lm > 0 && lm < valid && gl != gp);
      unsigned segm = (unsigned)bm & 0xFFFEu;

      int a = 0;
      while (a < valid) {
        unsigned hi = segm & ~((1u << (a + 1)) - 1u);
        int b = hi ? (int)__builtin_ctz(hi) : valid;
        int gs = __shfl(gl, a);
        if (gs != cur_g) {
          if (cur_g >= 0) flushf(cur_g);
          cur_g = gs;
        }
        int nq = q * 4;
        float m0 = (nq + 0 >= a && nq + 0 < b) ? wgt[0] : 0.f;
        float m1 = (nq + 1 >= a && nq + 1 < b) ? wgt[1] : 0.f;
        float m2 = (nq + 2 >= a && nq + 2 < b) ? wgt[2] : 0.f;
        float m3 = (nq + 3 >= a && nq + 3 < b) ? wgt[3] : 0.f;
        if (w == 0 && lm == 0) naccw += m0 + m1 + m2 + m3;
#pragma unroll
        for (int ctl = 0; ctl < 2; ++ctl) {
          f32x4 v = {0.f, 0.f, 0.f, 0.f};
          v = MFMA16(a0[0], Bv0[ctl][0], v);
          v = MFMA16(a0[1], Bv0[ctl][1], v);
          v = MFMA16(a0[2], Bv0[ctl][2], v);
          v = MFMA16(a0[3], Bv0[ctl][3], v);
          racc0[ctl] += m0 * v[0] + m1 * v[1] + m2 * v[2] + m3 * v[3];
        }
#pragma unroll
        for (int d = 0; d < 3; ++d) {
          f32x4 v = {0.f, 0.f, 0.f, 0.f};
          v = MFMA16(a1[d][0], Bv1[0], v);
          v = MFMA16(a1[d][1], Bv1[1], v);
          racc1[d] += m0 * v[0] + m1 * v[1] + m2 * v[2] + m3 * v[3];
        }
        if (has2) {
#pragma unroll
          for (int d = 0; d < 5; ++d) {
            f32x4 v = {0.f, 0.f, 0.f, 0.f};
            v = MFMA16(a2[d], Bv2, v);
            racc2[d] += m0 * v[0] + m1 * v[1] + m2 * v[2] + m3 * v[3];
          }
        }
        a = b;
      }
    }
  }
  if (cur_g >= 0) flushf(cur_g);
}

// ---------------------------------------------------------------------------
// finalize: out = num / max(norm, 1e-8)
// ---------------------------------------------------------------------------
__global__ __launch_bounds__(256) void finalize_kernel(
    float* __restrict__ out, const float* __restrict__ norm, int total) {
  int idx = blockIdx.x * blockDim.x + threadIdx.x;
  if (idx < total) {
    int g = idx / 480;
    out[idx] = out[idx] / fmaxf(norm[g], 1e-8f);
  }
}

extern "C" void kernel_launch(void* const* d_in, const int* in_sizes, int n_in,
                              void* d_out, int out_size, void* d_ws, size_t ws_size,
                              hipStream_t stream) {
  const float* f   = (const float*)d_in[0];
  const int* batch = (const int*)d_in[13];

  int N = in_sizes[0] / D_TOT;
  int G = out_size / D_TOT;

  // ws bytes: [0, 86016) Bpack bf16 (43008); [86016, ...) norm
  unsigned short* Bpack = (unsigned short*)d_ws;
  float* norm = (float*)((char*)d_ws + 86016);
  float* out  = (float*)d_out;

  hipMemsetAsync(d_out, 0, (size_t)out_size * sizeof(float), stream);
  hipMemsetAsync(norm, 0, (size_t)G * sizeof(float), stream);

  int lds128 = (128 * 129 + 32 * 128) * 4;   // 82432
  hipFuncSetAttribute((const void*)precompute_all,
                      hipFuncAttributeMaxDynamicSharedMemorySize, lds128);
  precompute_all<<<7, 256, lds128, stream>>>(
      (const float*)d_in[1], (const float*)d_in[2], (const float*)d_in[3],
      (const float*)d_in[4], (const float*)d_in[5], (const float*)d_in[6],
      (const float*)d_in[10], (const float*)d_in[11], (const float*)d_in[12],
      (const float*)d_in[7], (const float*)d_in[8], (const float*)d_in[9],
      Bpack);

  int ntiles = (N + 15) / 16;
  int nblocks = 512;                       // 2 blocks/CU (VGPR=128 => 2 waves/SIMD)
  if (nblocks > ntiles) nblocks = ntiles;
  int tpb = (ntiles + nblocks - 1) / nblocks;

  fused_stat_kernel<<<nblocks, 256, 0, stream>>>(
      f, Bpack, batch, out, norm, N, tpb, ntiles);

  finalize_kernel<<<(G * D_TOT + 255) / 256, 256, 0, stream>>>(out, norm, G * D_TOT);
}